// Round 1
// baseline (93.553 us; speedup 1.0000x reference)
//
#include <hip/hip_runtime.h>

#define NB 32
#define NC 256
#define HW 4096
#define AFWD 0.999f
#define EPS 1e-5f

// ---------------- Kernel 1: per-(b,c) mean & variance over H*W ----------------
__global__ __launch_bounds__(256) void cn_stats(const float* __restrict__ x,
                                                float* __restrict__ mu,
                                                float* __restrict__ v) {
    const int bc = blockIdx.x;                 // b*NC + c, 0..8191
    const float4* xp = (const float4*)(x + (size_t)bc * HW);
    const int t = threadIdx.x;
    float s = 0.f, ss = 0.f;
#pragma unroll
    for (int i = 0; i < 4; ++i) {
        float4 val = xp[t + i * 256];
        s  += val.x + val.y + val.z + val.w;
        ss += val.x * val.x + val.y * val.y + val.z * val.z + val.w * val.w;
    }
    // 64-lane wave reduction
#pragma unroll
    for (int off = 32; off > 0; off >>= 1) {
        s  += __shfl_down(s, off, 64);
        ss += __shfl_down(ss, off, 64);
    }
    __shared__ float sbuf[4], ssbuf[4];
    const int wave = t >> 6, lane = t & 63;
    if (lane == 0) { sbuf[wave] = s; ssbuf[wave] = ss; }
    __syncthreads();
    if (t == 0) {
        float S  = sbuf[0] + sbuf[1] + sbuf[2] + sbuf[3];
        float SS = ssbuf[0] + ssbuf[1] + ssbuf[2] + ssbuf[3];
        float mean = S * (1.f / HW);
        mu[bc] = mean;
        v[bc]  = SS * (1.f / HW) - mean * mean;   // E[x^2] - mu^2
    }
}

// ---------------- Kernel 2: batch-coupled EMA chain (tiny) ----------------
// One thread per channel c. Mirrors reference lin_momentum exactly.
__global__ __launch_bounds__(256) void cn_ema(const float* __restrict__ mu,
                                              const float* __restrict__ v,
                                              const float* __restrict__ m,
                                              const float* __restrict__ var,
                                              const float* __restrict__ m_p,
                                              const float* __restrict__ var_p,
                                              float* __restrict__ mu_stale,
                                              float* __restrict__ rscale) {
    const int c = threadIdx.x;                 // 0..255
    if (c >= NC) return;

    // pow_vec[j] = AFWD^(NB-1-j); p ends as AFWD^NB
    float powv[NB];
    float p = 1.f;
    for (int j = NB - 1; j >= 0; --j) { powv[j] = p; p *= AFWD; }
    const float mB = p;                        // AFWD^32
    const float one_m = 1.f - AFWD;

    // ---- lin_momentum(m_p, mu, m) ----
    float seq[2 * NB - 1];
    for (int i = 0; i < NB - 1; ++i) seq[i] = m_p[(i + 1) * NC + c];
    for (int i = 0; i < NB; ++i)     seq[NB - 1 + i] = mu[i * NC + c];

    float mu_new[NB];
    for (int i = 0; i < NB; ++i) {
        float tmp = 0.f;
        for (int j = 0; j < NB; ++j) tmp += powv[j] * seq[i + j];
        mu_new[i] = mB * m[i * NC + c] + one_m * tmp;
    }
    float mu_st[NB];
    mu_st[0] = m[(NB - 1) * NC + c];
    for (int i = 1; i < NB; ++i) mu_st[i] = mu_new[i - 1];

    // ---- var_current = v + AFWD*(mu - mu_stale)^2 ----
    float vc[NB];
    for (int i = 0; i < NB; ++i) {
        float d = mu[i * NC + c] - mu_st[i];
        vc[i] = v[i * NC + c] + AFWD * d * d;
    }

    // ---- lin_momentum(var_p, var_current, var) ----
    float seq2[2 * NB - 1];
    for (int i = 0; i < NB - 1; ++i) seq2[i] = var_p[(i + 1) * NC + c];
    for (int i = 0; i < NB; ++i)     seq2[NB - 1 + i] = vc[i];

    float var_new[NB];
    for (int i = 0; i < NB; ++i) {
        float tmp = 0.f;
        for (int j = 0; j < NB; ++j) tmp += powv[j] * seq2[i + j];
        var_new[i] = mB * var[i * NC + c] + one_m * tmp;
    }
    float var_st0 = var[(NB - 1) * NC + c];

    for (int i = 0; i < NB; ++i) {
        float vs = (i == 0) ? var_st0 : var_new[i - 1];
        mu_stale[i * NC + c] = mu_st[i];
        rscale[i * NC + c]   = 1.f / sqrtf(vs + EPS);
    }
}

// ---------------- Kernel 3: normalize ----------------
__global__ __launch_bounds__(256) void cn_norm(const float* __restrict__ x,
                                               const float* __restrict__ mu_stale,
                                               const float* __restrict__ rscale,
                                               float* __restrict__ out) {
    const int bc = blockIdx.x;
    const float mean = mu_stale[bc];
    const float rs   = rscale[bc];
    const float4* xp = (const float4*)(x + (size_t)bc * HW);
    float4* op       = (float4*)(out + (size_t)bc * HW);
    const int t = threadIdx.x;
#pragma unroll
    for (int i = 0; i < 4; ++i) {
        float4 val = xp[t + i * 256];
        float4 o;
        o.x = (val.x - mean) * rs;
        o.y = (val.y - mean) * rs;
        o.z = (val.z - mean) * rs;
        o.w = (val.w - mean) * rs;
        op[t + i * 256] = o;
    }
}

extern "C" void kernel_launch(void* const* d_in, const int* in_sizes, int n_in,
                              void* d_out, int out_size, void* d_ws, size_t ws_size,
                              hipStream_t stream) {
    const float* x     = (const float*)d_in[0];
    const float* m     = (const float*)d_in[1];
    const float* var   = (const float*)d_in[2];
    const float* m_p   = (const float*)d_in[3];
    const float* var_p = (const float*)d_in[4];
    float* out = (float*)d_out;

    float* ws = (float*)d_ws;
    float* mu       = ws;                 // [NB*NC]
    float* v        = ws + NB * NC;       // [NB*NC]
    float* mu_stale = ws + 2 * NB * NC;   // [NB*NC]
    float* rscale   = ws + 3 * NB * NC;   // [NB*NC]

    cn_stats<<<NB * NC, 256, 0, stream>>>(x, mu, v);
    cn_ema<<<1, 256, 0, stream>>>(mu, v, m, var, m_p, var_p, mu_stale, rscale);
    cn_norm<<<NB * NC, 256, 0, stream>>>(x, mu_stale, rscale, out);
}

// Round 2
// 67.109 us; speedup vs baseline: 1.3941x; 1.3941x over previous
//
#include <hip/hip_runtime.h>

#define NB 32
#define NC 256
#define HW 4096
#define AFWD 0.999f
#define EPS 1e-5f

typedef float f32x4 __attribute__((ext_vector_type(4)));

// ---------------- Kernel 1: per-(b,c) mean & variance over H*W ----------------
__global__ __launch_bounds__(256) void cn_stats(const float* __restrict__ x,
                                                float* __restrict__ mu,
                                                float* __restrict__ v) {
    const int bc = blockIdx.x;                 // b*NC + c, 0..8191
    const f32x4* xp = (const f32x4*)(x + (size_t)bc * HW);
    const int t = threadIdx.x;
    float s = 0.f, ss = 0.f;
#pragma unroll
    for (int i = 0; i < 4; ++i) {
        f32x4 val = xp[t + i * 256];
        s  += val.x + val.y + val.z + val.w;
        ss += val.x * val.x + val.y * val.y + val.z * val.z + val.w * val.w;
    }
#pragma unroll
    for (int off = 32; off > 0; off >>= 1) {
        s  += __shfl_down(s, off, 64);
        ss += __shfl_down(ss, off, 64);
    }
    __shared__ float sbuf[4], ssbuf[4];
    const int wave = t >> 6, lane = t & 63;
    if (lane == 0) { sbuf[wave] = s; ssbuf[wave] = ss; }
    __syncthreads();
    if (t == 0) {
        float S  = sbuf[0] + sbuf[1] + sbuf[2] + sbuf[3];
        float SS = ssbuf[0] + ssbuf[1] + ssbuf[2] + ssbuf[3];
        float mean = S * (1.f / HW);
        mu[bc] = mean;
        v[bc]  = SS * (1.f / HW) - mean * mean;   // E[x^2] - mu^2
    }
}

// ---------------- Kernel 2: batch-coupled EMA chain ----------------
// One block per channel c (256 blocks, 64 threads). All small arrays staged
// to LDS with one load per lane; window sums computed one-per-thread.
__global__ __launch_bounds__(64) void cn_ema(const float* __restrict__ mu,
                                             const float* __restrict__ v,
                                             const float* __restrict__ m,
                                             const float* __restrict__ var,
                                             const float* __restrict__ m_p,
                                             const float* __restrict__ var_p,
                                             float* __restrict__ mu_stale,
                                             float* __restrict__ rscale) {
    const int c = blockIdx.x;                  // 0..255
    const int t = threadIdx.x;                 // 0..63

    __shared__ float seq[2 * NB - 1];          // m_p[1:] ++ mu
    __shared__ float seq2[2 * NB - 1];         // var_p[1:] ++ var_current
    __shared__ float m_s[NB], v_s[NB], mu_s[NB], var_s[NB];
    __shared__ float mu_new[NB], mu_st[NB], var_new[NB];

    // ---- cooperative loads (each lane at most ~4 loads) ----
    if (t < NB - 1) seq[t]  = m_p[(t + 1) * NC + c];
    if (t < NB - 1) seq2[t] = var_p[(t + 1) * NC + c];
    if (t < NB) {
        float muv = mu[t * NC + c];
        mu_s[t] = muv;
        seq[NB - 1 + t] = muv;
        m_s[t]   = m[t * NC + c];
        v_s[t]   = v[t * NC + c];
        var_s[t] = var[t * NC + c];
    }

    // pow_vec[j] = AFWD^(NB-1-j); mB = AFWD^NB
    float powv[NB];
    float p = 1.f;
#pragma unroll
    for (int j = NB - 1; j >= 0; --j) { powv[j] = p; p *= AFWD; }
    const float mB = p;
    const float one_m = 1.f - AFWD;

    __syncthreads();

    // ---- mu chain: mu_new[i] = mB*m[i] + (1-a) * sum_j powv[j]*seq[i+j] ----
    if (t < NB) {
        float tmp = 0.f;
#pragma unroll
        for (int j = 0; j < NB; ++j) tmp += powv[j] * seq[t + j];
        mu_new[t] = mB * m_s[t] + one_m * tmp;
    }
    __syncthreads();

    // ---- stale mu, var_current ----
    if (t < NB) {
        float mst = (t == 0) ? m_s[NB - 1] : mu_new[t - 1];
        mu_st[t] = mst;
        float d = mu_s[t] - mst;
        seq2[NB - 1 + t] = v_s[t] + AFWD * d * d;
        mu_stale[t * NC + c] = mst;
    }
    __syncthreads();

    // ---- var chain ----
    if (t < NB) {
        float tmp = 0.f;
#pragma unroll
        for (int j = 0; j < NB; ++j) tmp += powv[j] * seq2[t + j];
        var_new[t] = mB * var_s[t] + one_m * tmp;
    }
    __syncthreads();

    if (t < NB) {
        float vs = (t == 0) ? var_s[NB - 1] : var_new[t - 1];
        rscale[t * NC + c] = 1.f / sqrtf(vs + EPS);
    }
}

// ---------------- Kernel 3: normalize (nontemporal stores) ----------------
__global__ __launch_bounds__(256) void cn_norm(const float* __restrict__ x,
                                               const float* __restrict__ mu_stale,
                                               const float* __restrict__ rscale,
                                               float* __restrict__ out) {
    const int bc = blockIdx.x;
    const float mean = mu_stale[bc];
    const float rs   = rscale[bc];
    const f32x4* xp = (const f32x4*)(x + (size_t)bc * HW);
    f32x4* op       = (f32x4*)(out + (size_t)bc * HW);
    const int t = threadIdx.x;
#pragma unroll
    for (int i = 0; i < 4; ++i) {
        f32x4 val = xp[t + i * 256];
        f32x4 o = (val - mean) * rs;
        __builtin_nontemporal_store(o, &op[t + i * 256]);
    }
}

extern "C" void kernel_launch(void* const* d_in, const int* in_sizes, int n_in,
                              void* d_out, int out_size, void* d_ws, size_t ws_size,
                              hipStream_t stream) {
    const float* x     = (const float*)d_in[0];
    const float* m     = (const float*)d_in[1];
    const float* var   = (const float*)d_in[2];
    const float* m_p   = (const float*)d_in[3];
    const float* var_p = (const float*)d_in[4];
    float* out = (float*)d_out;

    float* ws = (float*)d_ws;
    float* mu       = ws;                 // [NB*NC]
    float* v        = ws + NB * NC;       // [NB*NC]
    float* mu_stale = ws + 2 * NB * NC;   // [NB*NC]
    float* rscale   = ws + 3 * NB * NC;   // [NB*NC]

    cn_stats<<<NB * NC, 256, 0, stream>>>(x, mu, v);
    cn_ema<<<NC, 64, 0, stream>>>(mu, v, m, var, m_p, var_p, mu_stale, rscale);
    cn_norm<<<NB * NC, 256, 0, stream>>>(x, mu_stale, rscale, out);
}